// Round 28
// baseline (61.956 us; speedup 1.0000x reference)
//
#include <hip/hip_runtime.h>
#include <hip/hip_fp16.h>

// Hybrid MFMA + packed-f16-VALU kernel, INTERLEAVED block types.
// R27 evidence: co-scheduling works (VALUBusy 34->55%) but types were
// contiguous in blockIdx -> CUs held one type at a time; overlap partial.
// This round: groups of 7 blocks = 3 MFMA + 4 VALU (matches 768:1024 work
// ratio) so every CU holds both types from dispatch; (256,4) -> 4 resident
// blocks/CU. Fully-overlapped roofline: ~25us for the NN kernel.
//
// ws layout (floats):
//   [0      ,16384) minA0 : pc1_0 -> pc2   (cd, a->b)
//   [16384  ,32768) minB0 : pc2   -> pc1_0 (cd, b->a)
//   [32768  ,36864) minA1 : pc1_1 -> pc2   (seed, a->b)
//   [36864  ,53248) minB1 : pc2   -> pc1_1 (seed, b->a)
//   [53248  ,55296) minC  : pc3[b] -> pc2[b] (confidence, full f32)
//   [55296  ,55304) acc[8]
//   [55304]         ticket

#define N_MINS 55296

typedef _Float16 half8 __attribute__((ext_vector_type(8)));
typedef float f32x16 __attribute__((ext_vector_type(16)));

__device__ __forceinline__ float blockReduceSum(float v, float* sbuf) {
#pragma unroll
  for (int off = 32; off > 0; off >>= 1) v += __shfl_down(v, off, 64);
  int lane = threadIdx.x & 63;
  int wid  = threadIdx.x >> 6;
  if (lane == 0) sbuf[wid] = v;
  __syncthreads();
  float r = 0.f;
  if (threadIdx.x == 0) r = sbuf[0] + sbuf[1] + sbuf[2] + sbuf[3];
  return r;
}

// Block map (1856 blocks):
//   [0,1792): group g = blk/7, r = blk%7.
//     r<3  -> MFMA idx = g*3+r   (768 total: job1 512, job2a 256)
//     r>=3 -> VALU idx = g*4+r-3 (1024 total: job2b 512, job3 256, job4 256)
//   [1792,1856): conf (f32) pc3[b] -> pc2[b]
__global__ __launch_bounds__(256, 4) void k_nn_all(
    const float* __restrict__ pc10, const float* __restrict__ pc11,
    const float* __restrict__ pc2, const float* __restrict__ pc3,
    float* __restrict__ ws) {
  const int tid = threadIdx.x;
  const int blk = blockIdx.x;
  __shared__ uint4 smem4[1344];  // 21504 B (MFMA path); other paths reuse

  if (blk >= 1792) {  // confidence job, f32
    float4* tile4 = (float4*)smem4;
    int j = blk - 1792;
    if (j == 0 && tid < 9) ws[55296 + tid] = 0.f;  // zero acc[8] + ticket
    int b = j >> 3;
    int s = j & 7;
    int bi = b * 2048 + s * 256 + tid;
    {
      float bx = pc2[bi * 3 + 0], by = pc2[bi * 3 + 1], bz = pc2[bi * 3 + 2];
      tile4[tid] = make_float4(-2.f * bx, -2.f * by, -2.f * bz,
                               bx * bx + by * by + bz * bz);
    }
    int i = b * 256 + tid;
    float ax = pc3[i * 3 + 0], ay = pc3[i * 3 + 1], az = pc3[i * 3 + 2];
    float ra = ax * ax + ay * ay + az * az;
    __syncthreads();
    float mn = 3.0e38f;
#pragma unroll 4
    for (int t = 0; t < 256; ++t) {
      float4 q = tile4[t];
      float v = fmaf(q.x, ax, fmaf(q.y, ay, fmaf(q.z, az, q.w)));
      mn = fminf(mn, v);
    }
    atomicMin((unsigned int*)(ws + 53248 + i), __float_as_uint(fmaxf(mn + ra, 0.f)));
    return;
  }

  const int g = blk / 7;
  const int rr = blk - g * 7;

  if (rr >= 3) {  // ---- packed-f16 VALU path (R10-verified structure) ----
    int idx = g * 4 + (rr - 3);
    const float* A;
    const float* B;
    float* outMin;
    int aBase, bBase;
    if (idx < 512) {          // job2b: pc2 -> pc1_0, B in [8192,16384)
      A = pc2; B = pc10; outMin = ws + 16384;
      aBase = (idx >> 5) * 1024; bBase = 8192 + (idx & 31) * 256;
    } else if (idx < 768) {   // job3: pc1_1 (4096) -> pc2 (16384)
      int j = idx - 512;
      A = pc11; B = pc2; outMin = ws + 32768;
      aBase = (j >> 6) * 1024; bBase = (j & 63) * 256;
    } else {                  // job4: pc2 (16384) -> pc1_1 (4096)
      int j = idx - 768;
      A = pc2; B = pc11; outMin = ws + 36864;
      aBase = (j >> 4) * 1024; bBase = (j & 15) * 256;
    }

    float4* tile4 = (float4*)smem4;  // 128 entries, 2 KB
    if (tid < 128) {
      int bi0 = (bBase + 2 * tid) * 3;
      float x0 = B[bi0 + 0], y0 = B[bi0 + 1], z0 = B[bi0 + 2];
      float x1 = B[bi0 + 3], y1 = B[bi0 + 4], z1 = B[bi0 + 5];
      float4 e;
      e.x = __builtin_bit_cast(float, __floats2half2_rn(-2.f * x0, -2.f * x1));
      e.y = __builtin_bit_cast(float, __floats2half2_rn(-2.f * y0, -2.f * y1));
      e.z = __builtin_bit_cast(float, __floats2half2_rn(-2.f * z0, -2.f * z1));
      e.w = __builtin_bit_cast(float, __floats2half2_rn(
                x0 * x0 + y0 * y0 + z0 * z0, x1 * x1 + y1 * y1 + z1 * z1));
      tile4[tid] = e;
    }

    __half2 axx[4], ayy[4], azz[4];
    float mn2[4];  // bit-patterns of __half2 running minima
    float ra[4];
#pragma unroll
    for (int r = 0; r < 4; ++r) {
      int ai = aBase + r * 256 + tid;
      float ax = A[ai * 3 + 0];
      float ay = A[ai * 3 + 1];
      float az = A[ai * 3 + 2];
      axx[r] = __float2half2_rn(ax);
      ayy[r] = __float2half2_rn(ay);
      azz[r] = __float2half2_rn(az);
      ra[r] = fmaf(ax, ax, fmaf(ay, ay, az * az));
      mn2[r] = __builtin_bit_cast(float, 0x7BFF7BFFu);  // (65504, 65504)
    }
    __syncthreads();

#pragma unroll 4
    for (int p = 0; p < 128; ++p) {
      float4 q = tile4[p];
      __half2 qx = __builtin_bit_cast(__half2, q.x);
      __half2 qy = __builtin_bit_cast(__half2, q.y);
      __half2 qz = __builtin_bit_cast(__half2, q.z);
      __half2 qw = __builtin_bit_cast(__half2, q.w);
#pragma unroll
      for (int r = 0; r < 4; ++r) {
        __half2 v = __hfma2(qx, axx[r], __hfma2(qy, ayy[r], __hfma2(qz, azz[r], qw)));
        float vb = __builtin_bit_cast(float, v);
        asm("v_pk_min_f16 %0, %0, %1" : "+v"(mn2[r]) : "v"(vb));
      }
    }

#pragma unroll
    for (int r = 0; r < 4; ++r) {
      int ai = aBase + r * 256 + tid;
      __half2 m = __builtin_bit_cast(__half2, mn2[r]);
      float mnf = fminf(__low2float(m), __high2float(m));
      atomicMin((unsigned int*)(outMin + ai),
                __float_as_uint(fmaxf(mnf + ra[r], 0.f)));
    }
    return;
  }

  // ---- MFMA path (R16-verified config) ----
  int idx = g * 3 + rr;
  const float* A;
  const float* B;
  float* outMin;
  int aBase, bBase;
  if (idx < 512) {            // job1: pc1_0 (16384) -> pc2 (16384)
    A = pc10; B = pc2; outMin = ws + 0;
    aBase = (idx >> 3) * 256; bBase = (idx & 7) * 2048;
  } else {                    // job2a: pc2 (16384) -> pc1_0, B in [0,8192)
    int j = idx - 512;
    A = pc2; B = pc10; outMin = ws + 16384;
    aBase = (j >> 2) * 256; bBase = (j & 3) * 2048;
  }

  half8* bEnt = (half8*)smem4;            // 1024 entries, 16 KB
  half8* aEnt = (half8*)(smem4 + 1024);   // 256 entries, 4 KB
  float* aRa  = (float*)(smem4 + 1280);   // 256 f32, 1 KB

  // A entries (one per thread)
  {
    int ai = aBase + tid;
    float x = A[ai * 3 + 0], y = A[ai * 3 + 1], z = A[ai * 3 + 2];
    half8 e = {};
    e[0] = (_Float16)x; e[1] = (_Float16)y; e[2] = (_Float16)z;
    e[3] = (_Float16)1.f;
    aEnt[tid] = e;
    aRa[tid] = fmaf(x, x, fmaf(y, y, z * z));
  }
  // stage B chunk 0
#pragma unroll
  for (int e = tid; e < 1024; e += 256) {
    int bi = bBase + e;
    float x = B[bi * 3 + 0], y = B[bi * 3 + 1], z = B[bi * 3 + 2];
    half8 be = {};
    be[0] = (_Float16)(-2.f * x); be[1] = (_Float16)(-2.f * y);
    be[2] = (_Float16)(-2.f * z);
    be[3] = (_Float16)(fmaf(x, x, fmaf(y, y, z * z)));
    bEnt[e] = be;
  }
  __syncthreads();

  const int l = tid & 63;
  const int wid = tid >> 6;
  const int col = l & 31;
  half8 a80 = aEnt[wid * 64 + col];
  half8 a81 = aEnt[wid * 64 + 32 + col];

  f32x16 mn0, mn1, zc;
#pragma unroll
  for (int r = 0; r < 16; ++r) { mn0[r] = 3.0e38f; mn1[r] = 3.0e38f; zc[r] = 0.f; }

  for (int c = 0; c < 2; ++c) {
    if (c) {
      __syncthreads();
#pragma unroll
      for (int e = tid; e < 1024; e += 256) {
        int bi = bBase + 1024 + e;
        float x = B[bi * 3 + 0], y = B[bi * 3 + 1], z = B[bi * 3 + 2];
        half8 be = {};
        be[0] = (_Float16)(-2.f * x); be[1] = (_Float16)(-2.f * y);
        be[2] = (_Float16)(-2.f * z);
        be[3] = (_Float16)(fmaf(x, x, fmaf(y, y, z * z)));
        bEnt[e] = be;
      }
      __syncthreads();
    }
    for (int bt = 0; bt < 32; bt += 2) {
      half8 b0 = bEnt[bt * 32 + col];
      half8 b1 = bEnt[(bt + 1) * 32 + col];
      f32x16 c00 = __builtin_amdgcn_mfma_f32_32x32x16_f16(a80, b0, zc, 0, 0, 0);
      f32x16 c10 = __builtin_amdgcn_mfma_f32_32x32x16_f16(a81, b0, zc, 0, 0, 0);
      f32x16 c01 = __builtin_amdgcn_mfma_f32_32x32x16_f16(a80, b1, zc, 0, 0, 0);
      f32x16 c11 = __builtin_amdgcn_mfma_f32_32x32x16_f16(a81, b1, zc, 0, 0, 0);
#pragma unroll
      for (int r = 0; r < 16; ++r) {
        mn0[r] = fminf(fminf(mn0[r], c00[r]), c01[r]);  // -> v_min3_f32
        mn1[r] = fminf(fminf(mn1[r], c10[r]), c11[r]);
      }
    }
  }

  // min over the 32 cols (within each 32-lane half), then write 64 rows/wave
#pragma unroll
  for (int r = 0; r < 16; ++r) {
    float v0 = mn0[r], v1 = mn1[r];
    v0 = fminf(v0, __shfl_xor(v0, 1));
    v1 = fminf(v1, __shfl_xor(v1, 1));
    v0 = fminf(v0, __shfl_xor(v0, 2));
    v1 = fminf(v1, __shfl_xor(v1, 2));
    v0 = fminf(v0, __shfl_xor(v0, 4));
    v1 = fminf(v1, __shfl_xor(v1, 4));
    v0 = fminf(v0, __shfl_xor(v0, 8));
    v1 = fminf(v1, __shfl_xor(v1, 8));
    v0 = fminf(v0, __shfl_xor(v0, 16));
    v1 = fminf(v1, __shfl_xor(v1, 16));
    mn0[r] = v0;
    mn1[r] = v1;
  }
  if (col == 0) {
    int hi = l >> 5;
#pragma unroll
    for (int r = 0; r < 16; ++r) {
      int row = (r & 3) + 8 * (r >> 2) + 4 * hi;
      int a0 = aBase + wid * 64 + row;
      int a1 = a0 + 32;
      atomicMin((unsigned int*)(outMin + a0),
                __float_as_uint(fmaxf(fmaf(0.5f, mn0[r], aRa[wid * 64 + row]), 0.f)));
      atomicMin((unsigned int*)(outMin + a1),
                __float_as_uint(fmaxf(fmaf(0.5f, mn1[r], aRa[wid * 64 + 32 + row]), 0.f)));
    }
  }
}

// Segmented reduce + final combine (ticket: last block writes out).
__global__ __launch_bounds__(256) void k_reduce(
    const float* __restrict__ ws, const float* __restrict__ pc13,
    const float* __restrict__ pc10, const float* __restrict__ pc2,
    float* __restrict__ acc, unsigned int* __restrict__ ticket,
    float* __restrict__ out) {
  __shared__ float sbuf[4];
  int idx = blockIdx.x * 256 + threadIdx.x;
  float v;
  int k;
  if (idx < 53248) {
    v = sqrtf(fmaxf(ws[idx], 0.f));
    k = (idx < 16384) ? 0 : (idx < 32768) ? 1 : (idx < 36864) ? 2 : 3;
  } else if (idx < 55296) {
    int i = idx - 53248;
    float score = expf(-sqrtf(fmaxf(ws[idx], 0.f)));
    float d = pc13[i] - score;
    v = d * d;
    k = 4;
  } else {
    int i = idx - 55296;
    float d = pc10[i] - pc2[i];
    v = d * d;
    k = 5;
  }
  float s = blockReduceSum(v, sbuf);
  if (threadIdx.x == 0) {
    atomicAdd(acc + k, s);
    __threadfence();
    unsigned int t = atomicAdd(ticket, 1u);
    if (t == gridDim.x - 1) {
      __threadfence();
      float cd   = (acc[0] + acc[1]) * (1.f / 16384.f);
      float seed = acc[2] * (1.f / 4096.f) + acc[3] * (1.f / 16384.f);
      float conf = acc[4] * (1.f / 2048.f);
      float p2p  = acc[5] * (1.f / 49152.f);
      out[0] = 0.5f * cd + 0.5f * seed + 0.5f * conf + p2p;
    }
  }
}

extern "C" void kernel_launch(void* const* d_in, const int* in_sizes, int n_in,
                              void* d_out, int out_size, void* d_ws, size_t ws_size,
                              hipStream_t stream) {
  const float* pc10 = (const float*)d_in[0];
  const float* pc11 = (const float*)d_in[1];
  const float* pc13 = (const float*)d_in[2];
  const float* pc2  = (const float*)d_in[3];
  const float* pc3  = (const float*)d_in[4];
  float* ws  = (float*)d_ws;
  float* acc = ws + N_MINS;
  float* out = (float*)d_out;

  // init: min arrays to ~3.39e38 (0x7F7F7F7F); acc/ticket zeroed in k_nn_all
  (void)hipMemsetAsync(ws, 0x7F, N_MINS * sizeof(float), stream);

  k_nn_all<<<1856, 256, 0, stream>>>(pc10, pc11, pc2, pc3, ws);

  int reduce_blocks = (N_MINS + 49152) / 256;  // 408
  k_reduce<<<reduce_blocks, 256, 0, stream>>>(ws, pc13, pc10, pc2, acc,
                                              (unsigned int*)(ws + 55304), out);
}

// Round 29
// 54.841 us; speedup vs baseline: 1.1297x; 1.1297x over previous
//
#include <hip/hip_runtime.h>
#include <hip/hip_fp16.h>

// Hybrid MFMA + packed-f16-VALU kernel (R27 best-measured config, reverted
// after R28's interleave regression: contiguous dispatch lets short VALU
// blocks back-fill CUs as long MFMA blocks drain; forced mixing displaced
// MFMA residency and broke staging locality).
// Work split: MFMA = job1 + B[0,8192) of job2 (~60%); VALU = rest (~40%).
//
// ws layout (floats):
//   [0      ,16384) minA0 : pc1_0 -> pc2   (cd, a->b)
//   [16384  ,32768) minB0 : pc2   -> pc1_0 (cd, b->a)
//   [32768  ,36864) minA1 : pc1_1 -> pc2   (seed, a->b)
//   [36864  ,53248) minB1 : pc2   -> pc1_1 (seed, b->a)
//   [53248  ,55296) minC  : pc3[b] -> pc2[b] (confidence, full f32)
//   [55296  ,55304) acc[8]
//   [55304]         ticket

#define N_MINS 55296

typedef _Float16 half8 __attribute__((ext_vector_type(8)));
typedef float f32x16 __attribute__((ext_vector_type(16)));

__device__ __forceinline__ float blockReduceSum(float v, float* sbuf) {
#pragma unroll
  for (int off = 32; off > 0; off >>= 1) v += __shfl_down(v, off, 64);
  int lane = threadIdx.x & 63;
  int wid  = threadIdx.x >> 6;
  if (lane == 0) sbuf[wid] = v;
  __syncthreads();
  float r = 0.f;
  if (threadIdx.x == 0) r = sbuf[0] + sbuf[1] + sbuf[2] + sbuf[3];
  return r;
}

// Block map (1856 blocks):
//   [0   ,512 ) MFMA job1: pc1_0 -> pc2 (all B)
//   [512 ,768 ) MFMA job2a: pc2 -> pc1_0, B in [0,8192)
//   [768 ,832 ) conf (f32): pc3[b] -> pc2[b]
//   [832 ,1344) VALU job2b: pc2 -> pc1_0, B in [8192,16384)
//   [1344,1600) VALU job3: pc1_1 -> pc2
//   [1600,1856) VALU job4: pc2 -> pc1_1
__global__ __launch_bounds__(256, 3) void k_nn_all(
    const float* __restrict__ pc10, const float* __restrict__ pc11,
    const float* __restrict__ pc2, const float* __restrict__ pc3,
    float* __restrict__ ws) {
  const int tid = threadIdx.x;
  const int blk = blockIdx.x;
  __shared__ uint4 smem4[1344];  // 21504 B (MFMA path); other paths reuse

  if (blk >= 768 && blk < 832) {  // confidence job, f32
    float4* tile4 = (float4*)smem4;
    int j = blk - 768;
    if (j == 0 && tid < 9) ws[55296 + tid] = 0.f;  // zero acc[8] + ticket
    int b = j >> 3;
    int s = j & 7;
    int bi = b * 2048 + s * 256 + tid;
    {
      float bx = pc2[bi * 3 + 0], by = pc2[bi * 3 + 1], bz = pc2[bi * 3 + 2];
      tile4[tid] = make_float4(-2.f * bx, -2.f * by, -2.f * bz,
                               bx * bx + by * by + bz * bz);
    }
    int i = b * 256 + tid;
    float ax = pc3[i * 3 + 0], ay = pc3[i * 3 + 1], az = pc3[i * 3 + 2];
    float ra = ax * ax + ay * ay + az * az;
    __syncthreads();
    float mn = 3.0e38f;
#pragma unroll 4
    for (int t = 0; t < 256; ++t) {
      float4 q = tile4[t];
      float v = fmaf(q.x, ax, fmaf(q.y, ay, fmaf(q.z, az, q.w)));
      mn = fminf(mn, v);
    }
    atomicMin((unsigned int*)(ws + 53248 + i), __float_as_uint(fmaxf(mn + ra, 0.f)));
    return;
  }

  if (blk >= 832) {  // ---- packed-f16 VALU path (R10-verified structure) ----
    const float* A;
    const float* B;
    float* outMin;
    int aBase, bBase;
    if (blk < 1344) {         // job2b: pc2 -> pc1_0, B in [8192,16384)
      int j = blk - 832;
      A = pc2; B = pc10; outMin = ws + 16384;
      aBase = (j >> 5) * 1024; bBase = 8192 + (j & 31) * 256;
    } else if (blk < 1600) {  // job3: pc1_1 (4096) -> pc2 (16384)
      int j = blk - 1344;
      A = pc11; B = pc2; outMin = ws + 32768;
      aBase = (j >> 6) * 1024; bBase = (j & 63) * 256;
    } else {                  // job4: pc2 (16384) -> pc1_1 (4096)
      int j = blk - 1600;
      A = pc2; B = pc11; outMin = ws + 36864;
      aBase = (j >> 4) * 1024; bBase = (j & 15) * 256;
    }

    float4* tile4 = (float4*)smem4;  // 128 entries, 2 KB
    if (tid < 128) {
      int bi0 = (bBase + 2 * tid) * 3;
      float x0 = B[bi0 + 0], y0 = B[bi0 + 1], z0 = B[bi0 + 2];
      float x1 = B[bi0 + 3], y1 = B[bi0 + 4], z1 = B[bi0 + 5];
      float4 e;
      e.x = __builtin_bit_cast(float, __floats2half2_rn(-2.f * x0, -2.f * x1));
      e.y = __builtin_bit_cast(float, __floats2half2_rn(-2.f * y0, -2.f * y1));
      e.z = __builtin_bit_cast(float, __floats2half2_rn(-2.f * z0, -2.f * z1));
      e.w = __builtin_bit_cast(float, __floats2half2_rn(
                x0 * x0 + y0 * y0 + z0 * z0, x1 * x1 + y1 * y1 + z1 * z1));
      tile4[tid] = e;
    }

    __half2 axx[4], ayy[4], azz[4];
    float mn2[4];  // bit-patterns of __half2 running minima
    float ra[4];
#pragma unroll
    for (int r = 0; r < 4; ++r) {
      int ai = aBase + r * 256 + tid;
      float ax = A[ai * 3 + 0];
      float ay = A[ai * 3 + 1];
      float az = A[ai * 3 + 2];
      axx[r] = __float2half2_rn(ax);
      ayy[r] = __float2half2_rn(ay);
      azz[r] = __float2half2_rn(az);
      ra[r] = fmaf(ax, ax, fmaf(ay, ay, az * az));
      mn2[r] = __builtin_bit_cast(float, 0x7BFF7BFFu);  // (65504, 65504)
    }
    __syncthreads();

#pragma unroll 4
    for (int p = 0; p < 128; ++p) {
      float4 q = tile4[p];
      __half2 qx = __builtin_bit_cast(__half2, q.x);
      __half2 qy = __builtin_bit_cast(__half2, q.y);
      __half2 qz = __builtin_bit_cast(__half2, q.z);
      __half2 qw = __builtin_bit_cast(__half2, q.w);
#pragma unroll
      for (int r = 0; r < 4; ++r) {
        __half2 v = __hfma2(qx, axx[r], __hfma2(qy, ayy[r], __hfma2(qz, azz[r], qw)));
        float vb = __builtin_bit_cast(float, v);
        asm("v_pk_min_f16 %0, %0, %1" : "+v"(mn2[r]) : "v"(vb));
      }
    }

#pragma unroll
    for (int r = 0; r < 4; ++r) {
      int ai = aBase + r * 256 + tid;
      __half2 m = __builtin_bit_cast(__half2, mn2[r]);
      float mnf = fminf(__low2float(m), __high2float(m));
      atomicMin((unsigned int*)(outMin + ai),
                __float_as_uint(fmaxf(mnf + ra[r], 0.f)));
    }
    return;
  }

  // ---- MFMA path (R16-verified config) ----
  const float* A;
  const float* B;
  float* outMin;
  int aBase, bBase;
  if (blk < 512) {            // job1: pc1_0 (16384) -> pc2 (16384)
    A = pc10; B = pc2; outMin = ws + 0;
    aBase = (blk >> 3) * 256; bBase = (blk & 7) * 2048;
  } else {                    // job2a: pc2 (16384) -> pc1_0, B in [0,8192)
    int j = blk - 512;
    A = pc2; B = pc10; outMin = ws + 16384;
    aBase = (j >> 2) * 256; bBase = (j & 3) * 2048;
  }

  half8* bEnt = (half8*)smem4;            // 1024 entries, 16 KB
  half8* aEnt = (half8*)(smem4 + 1024);   // 256 entries, 4 KB
  float* aRa  = (float*)(smem4 + 1280);   // 256 f32, 1 KB

  // A entries (one per thread)
  {
    int ai = aBase + tid;
    float x = A[ai * 3 + 0], y = A[ai * 3 + 1], z = A[ai * 3 + 2];
    half8 e = {};
    e[0] = (_Float16)x; e[1] = (_Float16)y; e[2] = (_Float16)z;
    e[3] = (_Float16)1.f;
    aEnt[tid] = e;
    aRa[tid] = fmaf(x, x, fmaf(y, y, z * z));
  }
  // stage B chunk 0
#pragma unroll
  for (int e = tid; e < 1024; e += 256) {
    int bi = bBase + e;
    float x = B[bi * 3 + 0], y = B[bi * 3 + 1], z = B[bi * 3 + 2];
    half8 be = {};
    be[0] = (_Float16)(-2.f * x); be[1] = (_Float16)(-2.f * y);
    be[2] = (_Float16)(-2.f * z);
    be[3] = (_Float16)(fmaf(x, x, fmaf(y, y, z * z)));
    bEnt[e] = be;
  }
  __syncthreads();

  const int l = tid & 63;
  const int wid = tid >> 6;
  const int col = l & 31;
  half8 a80 = aEnt[wid * 64 + col];
  half8 a81 = aEnt[wid * 64 + 32 + col];

  f32x16 mn0, mn1, zc;
#pragma unroll
  for (int r = 0; r < 16; ++r) { mn0[r] = 3.0e38f; mn1[r] = 3.0e38f; zc[r] = 0.f; }

  for (int c = 0; c < 2; ++c) {
    if (c) {
      __syncthreads();
#pragma unroll
      for (int e = tid; e < 1024; e += 256) {
        int bi = bBase + 1024 + e;
        float x = B[bi * 3 + 0], y = B[bi * 3 + 1], z = B[bi * 3 + 2];
        half8 be = {};
        be[0] = (_Float16)(-2.f * x); be[1] = (_Float16)(-2.f * y);
        be[2] = (_Float16)(-2.f * z);
        be[3] = (_Float16)(fmaf(x, x, fmaf(y, y, z * z)));
        bEnt[e] = be;
      }
      __syncthreads();
    }
    for (int bt = 0; bt < 32; bt += 2) {
      half8 b0 = bEnt[bt * 32 + col];
      half8 b1 = bEnt[(bt + 1) * 32 + col];
      f32x16 c00 = __builtin_amdgcn_mfma_f32_32x32x16_f16(a80, b0, zc, 0, 0, 0);
      f32x16 c10 = __builtin_amdgcn_mfma_f32_32x32x16_f16(a81, b0, zc, 0, 0, 0);
      f32x16 c01 = __builtin_amdgcn_mfma_f32_32x32x16_f16(a80, b1, zc, 0, 0, 0);
      f32x16 c11 = __builtin_amdgcn_mfma_f32_32x32x16_f16(a81, b1, zc, 0, 0, 0);
#pragma unroll
      for (int r = 0; r < 16; ++r) {
        mn0[r] = fminf(fminf(mn0[r], c00[r]), c01[r]);  // -> v_min3_f32
        mn1[r] = fminf(fminf(mn1[r], c10[r]), c11[r]);
      }
    }
  }

  // min over the 32 cols (within each 32-lane half), then write 64 rows/wave
#pragma unroll
  for (int r = 0; r < 16; ++r) {
    float v0 = mn0[r], v1 = mn1[r];
    v0 = fminf(v0, __shfl_xor(v0, 1));
    v1 = fminf(v1, __shfl_xor(v1, 1));
    v0 = fminf(v0, __shfl_xor(v0, 2));
    v1 = fminf(v1, __shfl_xor(v1, 2));
    v0 = fminf(v0, __shfl_xor(v0, 4));
    v1 = fminf(v1, __shfl_xor(v1, 4));
    v0 = fminf(v0, __shfl_xor(v0, 8));
    v1 = fminf(v1, __shfl_xor(v1, 8));
    v0 = fminf(v0, __shfl_xor(v0, 16));
    v1 = fminf(v1, __shfl_xor(v1, 16));
    mn0[r] = v0;
    mn1[r] = v1;
  }
  if (col == 0) {
    int hi = l >> 5;
#pragma unroll
    for (int r = 0; r < 16; ++r) {
      int row = (r & 3) + 8 * (r >> 2) + 4 * hi;
      int a0 = aBase + wid * 64 + row;
      int a1 = a0 + 32;
      atomicMin((unsigned int*)(outMin + a0),
                __float_as_uint(fmaxf(fmaf(0.5f, mn0[r], aRa[wid * 64 + row]), 0.f)));
      atomicMin((unsigned int*)(outMin + a1),
                __float_as_uint(fmaxf(fmaf(0.5f, mn1[r], aRa[wid * 64 + 32 + row]), 0.f)));
    }
  }
}

// Segmented reduce + final combine (ticket: last block writes out).
__global__ __launch_bounds__(256) void k_reduce(
    const float* __restrict__ ws, const float* __restrict__ pc13,
    const float* __restrict__ pc10, const float* __restrict__ pc2,
    float* __restrict__ acc, unsigned int* __restrict__ ticket,
    float* __restrict__ out) {
  __shared__ float sbuf[4];
  int idx = blockIdx.x * 256 + threadIdx.x;
  float v;
  int k;
  if (idx < 53248) {
    v = sqrtf(fmaxf(ws[idx], 0.f));
    k = (idx < 16384) ? 0 : (idx < 32768) ? 1 : (idx < 36864) ? 2 : 3;
  } else if (idx < 55296) {
    int i = idx - 53248;
    float score = expf(-sqrtf(fmaxf(ws[idx], 0.f)));
    float d = pc13[i] - score;
    v = d * d;
    k = 4;
  } else {
    int i = idx - 55296;
    float d = pc10[i] - pc2[i];
    v = d * d;
    k = 5;
  }
  float s = blockReduceSum(v, sbuf);
  if (threadIdx.x == 0) {
    atomicAdd(acc + k, s);
    __threadfence();
    unsigned int t = atomicAdd(ticket, 1u);
    if (t == gridDim.x - 1) {
      __threadfence();
      float cd   = (acc[0] + acc[1]) * (1.f / 16384.f);
      float seed = acc[2] * (1.f / 4096.f) + acc[3] * (1.f / 16384.f);
      float conf = acc[4] * (1.f / 2048.f);
      float p2p  = acc[5] * (1.f / 49152.f);
      out[0] = 0.5f * cd + 0.5f * seed + 0.5f * conf + p2p;
    }
  }
}

extern "C" void kernel_launch(void* const* d_in, const int* in_sizes, int n_in,
                              void* d_out, int out_size, void* d_ws, size_t ws_size,
                              hipStream_t stream) {
  const float* pc10 = (const float*)d_in[0];
  const float* pc11 = (const float*)d_in[1];
  const float* pc13 = (const float*)d_in[2];
  const float* pc2  = (const float*)d_in[3];
  const float* pc3  = (const float*)d_in[4];
  float* ws  = (float*)d_ws;
  float* acc = ws + N_MINS;
  float* out = (float*)d_out;

  // init: min arrays to ~3.39e38 (0x7F7F7F7F); acc/ticket zeroed in k_nn_all
  (void)hipMemsetAsync(ws, 0x7F, N_MINS * sizeof(float), stream);

  k_nn_all<<<1856, 256, 0, stream>>>(pc10, pc11, pc2, pc3, ws);

  int reduce_blocks = (N_MINS + 49152) / 256;  // 408
  k_reduce<<<reduce_blocks, 256, 0, stream>>>(ws, pc13, pc10, pc2, acc,
                                              (unsigned int*)(ws + 55304), out);
}